// Round 15
// baseline (342.980 us; speedup 1.0000x reference)
//
#include <hip/hip_runtime.h>
#include <hip/hip_bf16.h>

static const int kN  = 25600;   // nodes
static const int kE  = 409600;  // edges
static const int kG  = 128;     // graphs
static const int kNPG = 200;    // nodes per graph
static const int kIN = 200;     // raw feat dim
static const int kIN2 = 400;    // after nan-mask concat
static const int kHB = 64;      // histogram blocks
static const int kEPB = kE / kHB;  // 6400 edges per histogram block
#define BN_EPS_ 1e-5f

typedef __attribute__((ext_vector_type(8))) short short8;
typedef __attribute__((ext_vector_type(4))) short short4v;
typedef __attribute__((ext_vector_type(4))) ushort us4;
typedef __attribute__((ext_vector_type(4))) float f32x4;

__device__ __forceinline__ float bu(ushort u) {
  union { float f; unsigned u32; } x; x.u32 = ((unsigned)u) << 16; return x.f;
}
__device__ __forceinline__ ushort f2u(float v) {
  __hip_bfloat16 t = __float2bfloat16(v);  // RN
  return *(ushort*)&t;
}
__device__ __forceinline__ float wredSum(float v) {
#pragma unroll
  for (int off = 1; off < 64; off <<= 1) v += __shfl_xor(v, off, 64);
  return v;
}
__device__ __forceinline__ float lrelu(float a) { return (a > 0.f) ? a : 0.2f * a; }

// ---------------- fused prep: prep_x (x4 vec) | Wt + wedot ----------------
// grid = 5000 + 720 + 3
__global__ void k_pre(const float* __restrict__ x, ushort* __restrict__ x2,
                      const float* __restrict__ W0, ushort* __restrict__ Wt0,
                      const float* __restrict__ W1, ushort* __restrict__ Wt1,
                      const float* __restrict__ W2, ushort* __restrict__ Wt2,
                      const float* __restrict__ We0, const float* __restrict__ ae0,
                      const float* __restrict__ We1, const float* __restrict__ ae1,
                      const float* __restrict__ We2, const float* __restrict__ ae2,
                      float* __restrict__ wed) {
  int b = blockIdx.x, tid = threadIdx.x;
  if (b < 5000) {
    int i4 = (b * 256 + tid) * 4;          // kIN=200 divisible by 4
    int n = i4 / kIN, j = i4 - n * kIN;
    float4 v = *(const float4*)&x[i4];
    ushort o0[4], o1[4];
    float vv[4] = {v.x, v.y, v.z, v.w};
#pragma unroll
    for (int q = 0; q < 4; q++) {
      bool bad = (vv[q] != vv[q]);
      o0[q] = f2u(bad ? 0.f : vv[q]);
      o1[q] = f2u(bad ? 1.f : 0.f);
    }
    *(us4*)&x2[(size_t)n * kIN2 + j] = *(us4*)o0;
    *(us4*)&x2[(size_t)n * kIN2 + kIN + j] = *(us4*)o1;
    return;
  }
  int pb = b - 5000;
  if (pb >= 720) {
    int l = pb - 720;
    const float* We = (l == 0) ? We0 : (l == 1) ? We1 : We2;
    const float* ae = (l == 0) ? ae0 : (l == 1) ? ae1 : ae2;
    int n = (l == 2) ? 64 : 256;
    float v = (tid < n) ? We[tid] * ae[tid] : 0.f;
    v = wredSum(v);
    if ((tid & 63) == 0 && tid < n) wed[l * 4 + (tid >> 6)] = v;
    return;
  }
  int i = pb * 256 + tid;
  if (i < 102400) {
    int n = i / kIN2, k = i - n * kIN2;            // N=256, K=400
    Wt0[(size_t)n * kIN2 + k] = f2u(W0[(size_t)k * 256 + n]);
  } else if (i < 102400 + 65536) {
    int j = i - 102400;
    int n = j >> 8, k = j & 255;                   // N=256, K=256
    Wt1[(size_t)n * 256 + k] = f2u(W1[(size_t)k * 256 + n]);
  } else {
    int j = i - 102400 - 65536;
    int n = j >> 8, k = j & 255;                   // N=64, K=256
    Wt2[(size_t)n * 256 + k] = f2u(W2[(size_t)k * 64 + n]);
  }
}

// ---------------- atomic-free degree: LDS histogram per 6400-edge chunk -----
__global__ __launch_bounds__(1024) void k_hist(const int* __restrict__ ei,
                                               int* __restrict__ epos,
                                               int* __restrict__ blockcnt) {
  __shared__ int cnt[kN];  // 100 KB
  int t = threadIdx.x, b = blockIdx.x;
  for (int i = t; i < kN; i += 1024) cnt[i] = 0;
  __syncthreads();
  int base = b * kEPB;
  for (int i = t; i < kEPB; i += 1024) {
    int e = base + i;
    int d = ei[kE + e];
    epos[e] = atomicAdd(&cnt[d], 1);  // LDS atomic
  }
  __syncthreads();
  for (int i = t; i < kN; i += 1024) blockcnt[(size_t)b * kN + i] = cnt[i];
}

// per-node: deg = sum over blocks; blockcnt <- exclusive prefix (in place)
__global__ void k_colscan(int* __restrict__ blockcnt, int* __restrict__ deg) {
  int n = blockIdx.x * 256 + threadIdx.x;
  int acc = 0;
#pragma unroll 8
  for (int b = 0; b < kHB; b++) {
    size_t idx = (size_t)b * kN + n;
    int v = blockcnt[idx];
    blockcnt[idx] = acc;
    acc += v;
  }
  deg[n] = acc;
}

// single-block exclusive scan of deg[25600] -> rowp (1024 thr x 25 elems)
__global__ void k_scan_all(const int* __restrict__ deg, int* __restrict__ rowp) {
  __shared__ int s[1024];
  int t = threadIdx.x;
  int base = t * 25;
  int loc[25];
  int sum = 0;
#pragma unroll
  for (int i = 0; i < 25; i++) { loc[i] = sum; sum += deg[base + i]; }
  s[t] = sum;
  __syncthreads();
  for (int off = 1; off < 1024; off <<= 1) {
    int v = (t >= off) ? s[t - off] : 0;
    __syncthreads();
    s[t] += v;
    __syncthreads();
  }
  int excl = s[t] - sum;
#pragma unroll
  for (int i = 0; i < 25; i++) rowp[base + i] = excl + loc[i];
}

// CSR row d = slots [rowp[d]+d, rowp[d]+d+deg[d]); self-loop handled in agg.
__global__ void k_scatter_n(const int* __restrict__ ei, const float* __restrict__ ea,
                            const int* __restrict__ rowp, const int* __restrict__ epos,
                            const int* __restrict__ blockcnt,
                            int* __restrict__ esrc, float* __restrict__ eaC) {
  int e = blockIdx.x * blockDim.x + threadIdx.x;
  if (e >= kE) return;
  int d = ei[kE + e];
  int b = e / kEPB;
  int slot = rowp[d] + d + blockcnt[(size_t)b * kN + d] + epos[e];
  esrc[slot] = ei[e];
  float v = ea[e];
  if (v != v) v = 0.f;
  eaC[slot] = v;
}

#define GBK 64
#define GPAD 72

// ---------------- MFMA GEMM + fused attention dots --------------------------
// A staged with nontemporal loads (read-once), B via normal (L2-reused) loads.
template <int BN, int MT>
__global__ __launch_bounds__(256) void k_gemm_f(const ushort* __restrict__ A,
                                                const ushort* __restrict__ Bt,
                                                ushort* __restrict__ C,
                                                const float* __restrict__ as_g,
                                                const float* __restrict__ ad_g,
                                                float* __restrict__ a_sg,
                                                float* __restrict__ a_dg, int K) {
  constexpr int MI = (BN == 256) ? (MT / 16) : 1;
  constexpr int H = (BN == 256) ? 4 : 1;
  __shared__ ushort As[MT * GPAD];
  __shared__ ushort Bs[BN * GPAD];
  int tid = threadIdx.x;
  int lane = tid & 63, w = tid >> 6;
  int l15 = lane & 15, l4 = lane >> 4;
  int row0 = blockIdx.y * MT;
  int wr = (BN == 256) ? 0 : (w * 16);
  int wc = (BN == 256) ? (w * 64) : 0;
  f32x4 acc[MI][4] = {};
  int ach = tid & 7, arow = tid >> 3;

  for (int kt = 0; kt < K; kt += GBK) {
    __syncthreads();
#pragma unroll
    for (int p = 0; p < MT / 32; p++) {
      int r = p * 32 + arow;
      int kg = kt + ach * 8;
      short8 v = {0, 0, 0, 0, 0, 0, 0, 0};
      if (kg < K)
        v = __builtin_nontemporal_load((const short8*)&A[(size_t)(row0 + r) * K + kg]);
      *(short8*)&As[r * GPAD + ach * 8] = v;
    }
#pragma unroll
    for (int p = 0; p < BN / 32; p++) {
      int r = p * 32 + arow;
      int kg = kt + ach * 8;
      short8 v = {0, 0, 0, 0, 0, 0, 0, 0};
      if (kg < K) v = *(const short8*)&Bt[(size_t)r * K + kg];
      *(short8*)&Bs[r * GPAD + ach * 8] = v;
    }
    __syncthreads();
#pragma unroll
    for (int kk = 0; kk < 2; kk++) {
      short8 af[MI], bf[4];
#pragma unroll
      for (int mi = 0; mi < MI; mi++)
        af[mi] = *(const short8*)&As[(wr + mi * 16 + l15) * GPAD + kk * 32 + l4 * 8];
#pragma unroll
      for (int ni = 0; ni < 4; ni++)
        bf[ni] = *(const short8*)&Bs[(wc + ni * 16 + l15) * GPAD + kk * 32 + l4 * 8];
#pragma unroll
      for (int mi = 0; mi < MI; mi++)
#pragma unroll
        for (int ni = 0; ni < 4; ni++)
          acc[mi][ni] = __builtin_amdgcn_mfma_f32_16x16x32_bf16(af[mi], bf[ni],
                                                                acc[mi][ni], 0, 0, 0);
    }
  }
#pragma unroll
  for (int mi = 0; mi < MI; mi++) {
    int rbase = row0 + wr + mi * 16 + l4 * 4;
#pragma unroll
    for (int ni = 0; ni < 4; ni++) {
      int col = wc + ni * 16 + l15;
#pragma unroll
      for (int r = 0; r < 4; r++)
        C[(size_t)(rbase + r) * BN + col] = f2u(acc[mi][ni][r]);
    }
  }
  float asv[4], adv[4];
#pragma unroll
  for (int ni = 0; ni < 4; ni++) {
    asv[ni] = as_g[wc + ni * 16 + l15];
    adv[ni] = ad_g[wc + ni * 16 + l15];
  }
  int hh = (BN == 256) ? w : 0;
#pragma unroll
  for (int mi = 0; mi < MI; mi++) {
#pragma unroll
    for (int r = 0; r < 4; r++) {
      float ps = 0.f, pd = 0.f;
#pragma unroll
      for (int ni = 0; ni < 4; ni++) {
        ps += acc[mi][ni][r] * asv[ni];
        pd += acc[mi][ni][r] * adv[ni];
      }
#pragma unroll
      for (int off = 1; off < 16; off <<= 1) {
        ps += __shfl_xor(ps, off, 64);
        pd += __shfl_xor(pd, off, 64);
      }
      if (l15 == 0) {
        int row = row0 + wr + mi * 16 + l4 * 4 + r;
        a_sg[row * H + hh] = ps;
        a_dg[row * H + hh] = pd;
      }
    }
  }
}

// ---------------- fused logit+softmax+aggregate, H=4, inline self-loop ------
// Output store is nontemporal (read exactly once as next GEMM's A) to keep
// L2 capacity for the hbuf gather table.
__global__ __launch_bounds__(256) void k_agg4(
    const ushort* __restrict__ hbuf, const int* __restrict__ rowp,
    const int* __restrict__ deg, const int* __restrict__ esrc,
    const float* __restrict__ eaC, const float* __restrict__ a_s,
    const float* __restrict__ a_d, const float* __restrict__ wed,
    const float* __restrict__ bias, const float* __restrict__ bng,
    const float* __restrict__ bnb, const float* __restrict__ bnm,
    const float* __restrict__ bnv, ushort* __restrict__ xout) {
  int tid = threadIdx.x;
  int w = tid >> 6, lane = tid & 63;
  int d = blockIdx.x * 4 + w;
  int start = rowp[d] + d;
  int dg = deg[d];
  int h = lane >> 4;
  float adh = a_d[d * 4 + h];
  float wdh = wed[h];

  int c0 = lane * 4;
  float a0 = 0.f, a1 = 0.f, a2 = 0.f, a3 = 0.f, sz = 0.f, sea = 0.f;
  int k = 0;
  for (; k + 4 <= dg; k += 4) {
    int s0 = esrc[start + k], s1 = esrc[start + k + 1];
    int s2 = esrc[start + k + 2], s3 = esrc[start + k + 3];
    float e0 = eaC[start + k], e1 = eaC[start + k + 1];
    float e2 = eaC[start + k + 2], e3 = eaC[start + k + 3];
    ushort4 v0 = *(const ushort4*)&hbuf[(size_t)s0 * 256 + c0];
    ushort4 v1 = *(const ushort4*)&hbuf[(size_t)s1 * 256 + c0];
    ushort4 v2 = *(const ushort4*)&hbuf[(size_t)s2 * 256 + c0];
    ushort4 v3 = *(const ushort4*)&hbuf[(size_t)s3 * 256 + c0];
    float w0 = __expf(lrelu(a_s[s0 * 4 + h] + adh + e0 * wdh));
    float w1 = __expf(lrelu(a_s[s1 * 4 + h] + adh + e1 * wdh));
    float w2 = __expf(lrelu(a_s[s2 * 4 + h] + adh + e2 * wdh));
    float w3 = __expf(lrelu(a_s[s3 * 4 + h] + adh + e3 * wdh));
    sea += (e0 + e1) + (e2 + e3);
    sz += (w0 + w1) + (w2 + w3);
    a0 += w0 * bu(v0.x) + w1 * bu(v1.x) + w2 * bu(v2.x) + w3 * bu(v3.x);
    a1 += w0 * bu(v0.y) + w1 * bu(v1.y) + w2 * bu(v2.y) + w3 * bu(v3.y);
    a2 += w0 * bu(v0.z) + w1 * bu(v1.z) + w2 * bu(v2.z) + w3 * bu(v3.z);
    a3 += w0 * bu(v0.w) + w1 * bu(v1.w) + w2 * bu(v2.w) + w3 * bu(v3.w);
  }
  for (; k < dg; k++) {
    int s0 = esrc[start + k];
    float e0 = eaC[start + k];
    ushort4 v0 = *(const ushort4*)&hbuf[(size_t)s0 * 256 + c0];
    float w0 = __expf(lrelu(a_s[s0 * 4 + h] + adh + e0 * wdh));
    sea += e0;
    sz += w0;
    a0 += w0 * bu(v0.x); a1 += w0 * bu(v0.y);
    a2 += w0 * bu(v0.z); a3 += w0 * bu(v0.w);
  }
  // self-loop: lea = mean incoming ea, src = d
  {
    float lea = sea / fmaxf((float)dg, 1.f);
    ushort4 v0 = *(const ushort4*)&hbuf[(size_t)d * 256 + c0];
    float w0 = __expf(lrelu(a_s[d * 4 + h] + adh + lea * wdh));
    sz += w0;
    a0 += w0 * bu(v0.x); a1 += w0 * bu(v0.y);
    a2 += w0 * bu(v0.z); a3 += w0 * bu(v0.w);
  }
  float winv = 1.f / (sz + 1e-16f);

  float4 bi = *(const float4*)&bias[c0];
  a0 = a0 * winv + bi.x; a1 = a1 * winv + bi.y;
  a2 = a2 * winv + bi.z; a3 = a3 * winv + bi.w;
  float4 g4 = *(const float4*)&bng[c0], b4 = *(const float4*)&bnb[c0];
  float4 m4 = *(const float4*)&bnm[c0], v4 = *(const float4*)&bnv[c0];
  a0 = fmaxf((a0 - m4.x) * rsqrtf(v4.x + BN_EPS_) * g4.x + b4.x, 0.f);
  a1 = fmaxf((a1 - m4.y) * rsqrtf(v4.y + BN_EPS_) * g4.y + b4.y, 0.f);
  a2 = fmaxf((a2 - m4.z) * rsqrtf(v4.z + BN_EPS_) * g4.z + b4.z, 0.f);
  a3 = fmaxf((a3 - m4.w) * rsqrtf(v4.w + BN_EPS_) * g4.w + b4.w, 0.f);
  us4 o = {(ushort)f2u(a0), (ushort)f2u(a1), (ushort)f2u(a2), (ushort)f2u(a3)};
  __builtin_nontemporal_store(o, (us4*)&xout[(size_t)d * 256 + c0]);
}

// ---------------- final agg (H=1, 64 ch), inline self-loop ------------------
__global__ __launch_bounds__(256) void k_agg1(
    const ushort* __restrict__ hbuf, const int* __restrict__ rowp,
    const int* __restrict__ deg, const int* __restrict__ esrc,
    const float* __restrict__ eaC, const float* __restrict__ a_s,
    const float* __restrict__ a_d, const float* __restrict__ wed,
    const float* __restrict__ bias, float* __restrict__ xout) {
  int tid = threadIdx.x;
  int w = tid >> 6, lane = tid & 63;
  int d = blockIdx.x * 4 + w;
  int start = rowp[d] + d;
  int dg = deg[d];
  float adh = a_d[d];
  float wdh = wed[0];

  float acc = 0.f, sz = 0.f, sea = 0.f;
  int k = 0;
  for (; k + 4 <= dg; k += 4) {
    int s0 = esrc[start + k], s1 = esrc[start + k + 1];
    int s2 = esrc[start + k + 2], s3 = esrc[start + k + 3];
    float e0 = eaC[start + k], e1 = eaC[start + k + 1];
    float e2 = eaC[start + k + 2], e3 = eaC[start + k + 3];
    float v0 = bu(hbuf[(size_t)s0 * 64 + lane]);
    float v1 = bu(hbuf[(size_t)s1 * 64 + lane]);
    float v2 = bu(hbuf[(size_t)s2 * 64 + lane]);
    float v3 = bu(hbuf[(size_t)s3 * 64 + lane]);
    float w0 = __expf(lrelu(a_s[s0] + adh + e0 * wdh));
    float w1 = __expf(lrelu(a_s[s1] + adh + e1 * wdh));
    float w2 = __expf(lrelu(a_s[s2] + adh + e2 * wdh));
    float w3 = __expf(lrelu(a_s[s3] + adh + e3 * wdh));
    sea += (e0 + e1) + (e2 + e3);
    sz += (w0 + w1) + (w2 + w3);
    acc += w0 * v0 + w1 * v1 + w2 * v2 + w3 * v3;
  }
  for (; k < dg; k++) {
    int s0 = esrc[start + k];
    float e0 = eaC[start + k];
    float w0 = __expf(lrelu(a_s[s0] + adh + e0 * wdh));
    sea += e0;
    sz += w0;
    acc += w0 * bu(hbuf[(size_t)s0 * 64 + lane]);
  }
  {
    float lea = sea / fmaxf((float)dg, 1.f);
    float w0 = __expf(lrelu(a_s[d] + adh + lea * wdh));
    sz += w0;
    acc += w0 * bu(hbuf[(size_t)d * 64 + lane]);
  }
  acc = acc / (sz + 1e-16f) + bias[lane];
  __builtin_nontemporal_store(acc, &xout[(size_t)d * 64 + lane]);
}

// ---------------- fused mean-pool + MLP head ----------------
__global__ void k_poolhead(const float* __restrict__ xin,
                           const float* __restrict__ cw1, const float* __restrict__ cb1,
                           const float* __restrict__ cw2, const float* __restrict__ cb2,
                           float* __restrict__ out) {
  __shared__ float part[4][64];
  __shared__ float gb[64], hb[64];
  int g = blockIdx.x, tid = threadIdx.x;
  int c = tid & 63, w = tid >> 6;
  float acc = 0.f;
  size_t base = (size_t)g * kNPG * 64;
  for (int n = w; n < kNPG; n += 4) acc += xin[base + (size_t)n * 64 + c];
  part[w][c] = acc;
  __syncthreads();
  if (tid < 64) {
    float s = (part[0][c] + part[1][c]) + (part[2][c] + part[3][c]);
    gb[c] = s * (1.f / kNPG);
  }
  __syncthreads();
  if (tid < 64) {
    float s = cb1[c];
#pragma unroll 8
    for (int i = 0; i < 64; i++) s += gb[i] * cw1[i * 64 + c];
    s = 0.5f * s * (1.f + erff(s * 0.70710678118654752f));  // exact GELU
    hb[c] = s;
  }
  __syncthreads();
  if (tid < 2) {
    float o = cb2[tid];
    for (int i = 0; i < 64; i++) o += hb[i] * cw2[i * 2 + tid];
    out[g * 2 + tid] = o;
  }
}

// ---------------- launch ----------------

extern "C" void kernel_launch(void* const* d_in, const int* in_sizes, int n_in,
                              void* d_out, int out_size, void* d_ws, size_t ws_size,
                              hipStream_t stream) {
  (void)in_sizes; (void)n_in; (void)out_size; (void)ws_size;
  const float* x  = (const float*)d_in[0];
  const int* ei   = (const int*)d_in[1];
  const float* ea = (const float*)d_in[2];
  const float *W[3], *as_[3], *ad_[3], *We[3], *ae[3], *bi[3];
  for (int l = 0; l < 3; l++) {
    W[l]   = (const float*)d_in[4 + l * 6 + 0];
    as_[l] = (const float*)d_in[4 + l * 6 + 1];
    ad_[l] = (const float*)d_in[4 + l * 6 + 2];
    We[l]  = (const float*)d_in[4 + l * 6 + 3];
    ae[l]  = (const float*)d_in[4 + l * 6 + 4];
    bi[l]  = (const float*)d_in[4 + l * 6 + 5];
  }
  const float* bng = (const float*)d_in[22];
  const float* bnb = (const float*)d_in[23];
  const float* bnm = (const float*)d_in[24];
  const float* bnv = (const float*)d_in[25];
  const float* cw1 = (const float*)d_in[26];
  const float* cb1 = (const float*)d_in[27];
  const float* cw2 = (const float*)d_in[28];
  const float* cb2 = (const float*)d_in[29];

  char* p = (char*)d_ws;
  auto alloc = [&](size_t bytes) -> void* {
    void* r = (void*)p;
    p += (bytes + 255) & ~(size_t)255;
    return r;
  };
  ushort* x2b   = (ushort*)alloc((size_t)kN * kIN2 * 2);
  ushort* hbufb = (ushort*)alloc((size_t)kN * 256 * 2);
  ushort* xbA   = (ushort*)alloc((size_t)kN * 256 * 2);
  ushort* xbB   = (ushort*)alloc((size_t)kN * 256 * 2);
  float*  fbuf  = (float*)alloc((size_t)kN * 64 * 4);
  ushort* Wt0   = (ushort*)alloc((size_t)kIN2 * 256 * 2);
  ushort* Wt1   = (ushort*)alloc((size_t)256 * 256 * 2);
  ushort* Wt2   = (ushort*)alloc((size_t)256 * 64 * 2);
  float* a_s    = (float*)alloc((size_t)kN * 4 * 4);
  float* a_d    = (float*)alloc((size_t)kN * 4 * 4);
  int* rowp     = (int*)alloc((size_t)kN * 4);
  int* esrc     = (int*)alloc((size_t)(kE + kN) * 4);
  float* eaC    = (float*)alloc((size_t)(kE + kN) * 4);
  int* epos     = (int*)alloc((size_t)kE * 4);
  int* blockcnt = (int*)alloc((size_t)kHB * kN * 4);   // 6.55 MB
  float* wed    = (float*)alloc(256);
  int* deg      = (int*)alloc((size_t)kN * 4);

  // 1: fused prep (prep_x x4 | Wt + wedot)
  k_pre<<<5000 + 720 + 3, 256, 0, stream>>>(x, x2b, W[0], Wt0, W[1], Wt1,
                                            W[2], Wt2, We[0], ae[0], We[1], ae[1],
                                            We[2], ae[2], wed);
  // 2-5: atomic-free CSR build
  k_hist<<<kHB, 1024, 0, stream>>>(ei, epos, blockcnt);
  k_colscan<<<kN / 256, 256, 0, stream>>>(blockcnt, deg);
  k_scan_all<<<1, 1024, 0, stream>>>(deg, rowp);
  k_scatter_n<<<(kE + 255) / 256, 256, 0, stream>>>(ei, ea, rowp, epos, blockcnt,
                                                    esrc, eaC);
  // 6: layer-0 GEMM (K=400)
  dim3 gg32(1, kN / 32);
  k_gemm_f<256, 32><<<gg32, 256, 0, stream>>>(x2b, Wt0, hbufb, as_[0], ad_[0],
                                              a_s, a_d, kIN2);
  // 7: agg layer0
  k_agg4<<<kN / 4, 256, 0, stream>>>(hbufb, rowp, deg, esrc, eaC, a_s, a_d,
                                     &wed[0], bi[0], bng, bnb, bnm, bnv, xbA);
  // 8: gemm layer1
  k_gemm_f<256, 32><<<gg32, 256, 0, stream>>>(xbA, Wt1, hbufb, as_[1], ad_[1],
                                              a_s, a_d, 256);
  // 9: agg layer1
  k_agg4<<<kN / 4, 256, 0, stream>>>(hbufb, rowp, deg, esrc, eaC, a_s, a_d,
                                     &wed[4], bi[1], bng, bnb, bnm, bnv, xbB);
  // 10: gemm layer2
  dim3 gg64(1, kN / 64);
  k_gemm_f<64, 64><<<gg64, 256, 0, stream>>>(xbB, Wt2, hbufb, as_[2], ad_[2],
                                             a_s, a_d, 256);
  // 11: agg layer2 (H=1)
  k_agg1<<<kN / 4, 256, 0, stream>>>(hbufb, rowp, deg, esrc, eaC, a_s, a_d,
                                     &wed[8], bi[2], fbuf);
  // 12: pool + MLP head
  k_poolhead<<<kG, 256, 0, stream>>>(fbuf, cw1, cb1, cw2, cb2, (float*)d_out);
}

// Round 16
// 329.714 us; speedup vs baseline: 1.0402x; 1.0402x over previous
//
#include <hip/hip_runtime.h>
#include <hip/hip_bf16.h>

static const int kN  = 25600;   // nodes
static const int kE  = 409600;  // edges
static const int kG  = 128;     // graphs
static const int kNPG = 200;    // nodes per graph
static const int kIN = 200;     // raw feat dim
static const int kIN2 = 400;    // after nan-mask concat
static const int kHB = 64;      // histogram blocks
static const int kEPB = kE / kHB;  // 6400 edges per histogram block
#define BN_EPS_ 1e-5f

typedef __attribute__((ext_vector_type(8))) short short8;
typedef __attribute__((ext_vector_type(4))) ushort us4;
typedef __attribute__((ext_vector_type(4))) float f32x4;

__device__ __forceinline__ float bu(ushort u) {
  union { float f; unsigned u32; } x; x.u32 = ((unsigned)u) << 16; return x.f;
}
__device__ __forceinline__ ushort f2u(float v) {
  __hip_bfloat16 t = __float2bfloat16(v);  // RN
  return *(ushort*)&t;
}
__device__ __forceinline__ float wredSum(float v) {
#pragma unroll
  for (int off = 1; off < 64; off <<= 1) v += __shfl_xor(v, off, 64);
  return v;
}
__device__ __forceinline__ float lrelu(float a) { return (a > 0.f) ? a : 0.2f * a; }

// ---------------- fused prep: prep_x (x4 vec) | Wt + wedot ----------------
// grid = 5000 + 720 + 3
__global__ void k_pre(const float* __restrict__ x, ushort* __restrict__ x2,
                      const float* __restrict__ W0, ushort* __restrict__ Wt0,
                      const float* __restrict__ W1, ushort* __restrict__ Wt1,
                      const float* __restrict__ W2, ushort* __restrict__ Wt2,
                      const float* __restrict__ We0, const float* __restrict__ ae0,
                      const float* __restrict__ We1, const float* __restrict__ ae1,
                      const float* __restrict__ We2, const float* __restrict__ ae2,
                      float* __restrict__ wed) {
  int b = blockIdx.x, tid = threadIdx.x;
  if (b < 5000) {
    int i4 = (b * 256 + tid) * 4;          // kIN=200 divisible by 4
    int n = i4 / kIN, j = i4 - n * kIN;
    float4 v = *(const float4*)&x[i4];
    ushort o0[4], o1[4];
    float vv[4] = {v.x, v.y, v.z, v.w};
#pragma unroll
    for (int q = 0; q < 4; q++) {
      bool bad = (vv[q] != vv[q]);
      o0[q] = f2u(bad ? 0.f : vv[q]);
      o1[q] = f2u(bad ? 1.f : 0.f);
    }
    *(us4*)&x2[(size_t)n * kIN2 + j] = *(us4*)o0;
    *(us4*)&x2[(size_t)n * kIN2 + kIN + j] = *(us4*)o1;
    return;
  }
  int pb = b - 5000;
  if (pb >= 720) {
    int l = pb - 720;
    const float* We = (l == 0) ? We0 : (l == 1) ? We1 : We2;
    const float* ae = (l == 0) ? ae0 : (l == 1) ? ae1 : ae2;
    int n = (l == 2) ? 64 : 256;
    float v = (tid < n) ? We[tid] * ae[tid] : 0.f;
    v = wredSum(v);
    if ((tid & 63) == 0 && tid < n) wed[l * 4 + (tid >> 6)] = v;
    return;
  }
  int i = pb * 256 + tid;
  if (i < 102400) {
    int n = i / kIN2, k = i - n * kIN2;            // N=256, K=400
    Wt0[(size_t)n * kIN2 + k] = f2u(W0[(size_t)k * 256 + n]);
  } else if (i < 102400 + 65536) {
    int j = i - 102400;
    int n = j >> 8, k = j & 255;                   // N=256, K=256
    Wt1[(size_t)n * 256 + k] = f2u(W1[(size_t)k * 256 + n]);
  } else {
    int j = i - 102400 - 65536;
    int n = j >> 8, k = j & 255;                   // N=64, K=256
    Wt2[(size_t)n * 256 + k] = f2u(W2[(size_t)k * 64 + n]);
  }
}

// ---------------- atomic-free degree: LDS histogram per 6400-edge chunk -----
__global__ __launch_bounds__(1024) void k_hist(const int* __restrict__ ei,
                                               int* __restrict__ epos,
                                               int* __restrict__ blockcnt) {
  __shared__ int cnt[kN];  // 100 KB
  int t = threadIdx.x, b = blockIdx.x;
  for (int i = t; i < kN; i += 1024) cnt[i] = 0;
  __syncthreads();
  int base = b * kEPB;
  for (int i = t; i < kEPB; i += 1024) {
    int e = base + i;
    int d = ei[kE + e];
    epos[e] = atomicAdd(&cnt[d], 1);  // LDS atomic
  }
  __syncthreads();
  for (int i = t; i < kN; i += 1024) blockcnt[(size_t)b * kN + i] = cnt[i];
}

// per-node: deg = sum over blocks; blockcnt <- exclusive prefix (in place)
__global__ void k_colscan(int* __restrict__ blockcnt, int* __restrict__ deg) {
  int n = blockIdx.x * 256 + threadIdx.x;
  int acc = 0;
#pragma unroll 8
  for (int b = 0; b < kHB; b++) {
    size_t idx = (size_t)b * kN + n;
    int v = blockcnt[idx];
    blockcnt[idx] = acc;
    acc += v;
  }
  deg[n] = acc;
}

// single-block exclusive scan of deg[25600] -> rowp (1024 thr x 25 elems)
__global__ void k_scan_all(const int* __restrict__ deg, int* __restrict__ rowp) {
  __shared__ int s[1024];
  int t = threadIdx.x;
  int base = t * 25;
  int loc[25];
  int sum = 0;
#pragma unroll
  for (int i = 0; i < 25; i++) { loc[i] = sum; sum += deg[base + i]; }
  s[t] = sum;
  __syncthreads();
  for (int off = 1; off < 1024; off <<= 1) {
    int v = (t >= off) ? s[t - off] : 0;
    __syncthreads();
    s[t] += v;
    __syncthreads();
  }
  int excl = s[t] - sum;
#pragma unroll
  for (int i = 0; i < 25; i++) rowp[base + i] = excl + loc[i];
}

// CSR row d = slots [rowp[d]+d, rowp[d]+d+deg[d]); self-loop handled in agg.
__global__ void k_scatter_n(const int* __restrict__ ei, const float* __restrict__ ea,
                            const int* __restrict__ rowp, const int* __restrict__ epos,
                            const int* __restrict__ blockcnt,
                            int* __restrict__ esrc, float* __restrict__ eaC) {
  int e = blockIdx.x * blockDim.x + threadIdx.x;
  if (e >= kE) return;
  int d = ei[kE + e];
  int b = e / kEPB;
  int slot = rowp[d] + d + blockcnt[(size_t)b * kN + d] + epos[e];
  esrc[slot] = ei[e];
  float v = ea[e];
  if (v != v) v = 0.f;
  eaC[slot] = v;
}

#define GBK 64
#define GPAD 72

// ---------------- MFMA GEMM + fused attention dots --------------------------
template <int BN, int MT>
__global__ __launch_bounds__(256) void k_gemm_f(const ushort* __restrict__ A,
                                                const ushort* __restrict__ Bt,
                                                ushort* __restrict__ C,
                                                const float* __restrict__ as_g,
                                                const float* __restrict__ ad_g,
                                                float* __restrict__ a_sg,
                                                float* __restrict__ a_dg, int K) {
  constexpr int MI = (BN == 256) ? (MT / 16) : 1;
  constexpr int H = (BN == 256) ? 4 : 1;
  __shared__ ushort As[MT * GPAD];
  __shared__ ushort Bs[BN * GPAD];
  int tid = threadIdx.x;
  int lane = tid & 63, w = tid >> 6;
  int l15 = lane & 15, l4 = lane >> 4;
  int row0 = blockIdx.y * MT;
  int wr = (BN == 256) ? 0 : (w * 16);
  int wc = (BN == 256) ? (w * 64) : 0;
  f32x4 acc[MI][4] = {};
  int ach = tid & 7, arow = tid >> 3;

  for (int kt = 0; kt < K; kt += GBK) {
    __syncthreads();
#pragma unroll
    for (int p = 0; p < MT / 32; p++) {
      int r = p * 32 + arow;
      int kg = kt + ach * 8;
      short8 v = {0, 0, 0, 0, 0, 0, 0, 0};
      if (kg < K) v = *(const short8*)&A[(size_t)(row0 + r) * K + kg];
      *(short8*)&As[r * GPAD + ach * 8] = v;
    }
#pragma unroll
    for (int p = 0; p < BN / 32; p++) {
      int r = p * 32 + arow;
      int kg = kt + ach * 8;
      short8 v = {0, 0, 0, 0, 0, 0, 0, 0};
      if (kg < K) v = *(const short8*)&Bt[(size_t)r * K + kg];
      *(short8*)&Bs[r * GPAD + ach * 8] = v;
    }
    __syncthreads();
#pragma unroll
    for (int kk = 0; kk < 2; kk++) {
      short8 af[MI], bf[4];
#pragma unroll
      for (int mi = 0; mi < MI; mi++)
        af[mi] = *(const short8*)&As[(wr + mi * 16 + l15) * GPAD + kk * 32 + l4 * 8];
#pragma unroll
      for (int ni = 0; ni < 4; ni++)
        bf[ni] = *(const short8*)&Bs[(wc + ni * 16 + l15) * GPAD + kk * 32 + l4 * 8];
#pragma unroll
      for (int mi = 0; mi < MI; mi++)
#pragma unroll
        for (int ni = 0; ni < 4; ni++)
          acc[mi][ni] = __builtin_amdgcn_mfma_f32_16x16x32_bf16(af[mi], bf[ni],
                                                                acc[mi][ni], 0, 0, 0);
    }
  }
#pragma unroll
  for (int mi = 0; mi < MI; mi++) {
    int rbase = row0 + wr + mi * 16 + l4 * 4;
#pragma unroll
    for (int ni = 0; ni < 4; ni++) {
      int col = wc + ni * 16 + l15;
#pragma unroll
      for (int r = 0; r < 4; r++)
        C[(size_t)(rbase + r) * BN + col] = f2u(acc[mi][ni][r]);
    }
  }
  float asv[4], adv[4];
#pragma unroll
  for (int ni = 0; ni < 4; ni++) {
    asv[ni] = as_g[wc + ni * 16 + l15];
    adv[ni] = ad_g[wc + ni * 16 + l15];
  }
  int hh = (BN == 256) ? w : 0;
#pragma unroll
  for (int mi = 0; mi < MI; mi++) {
#pragma unroll
    for (int r = 0; r < 4; r++) {
      float ps = 0.f, pd = 0.f;
#pragma unroll
      for (int ni = 0; ni < 4; ni++) {
        ps += acc[mi][ni][r] * asv[ni];
        pd += acc[mi][ni][r] * adv[ni];
      }
#pragma unroll
      for (int off = 1; off < 16; off <<= 1) {
        ps += __shfl_xor(ps, off, 64);
        pd += __shfl_xor(pd, off, 64);
      }
      if (l15 == 0) {
        int row = row0 + wr + mi * 16 + l4 * 4 + r;
        a_sg[row * H + hh] = ps;
        a_dg[row * H + hh] = pd;
      }
    }
  }
}

// ---------------- fused logit+softmax+aggregate, H=4, inline self-loop ------
__global__ __launch_bounds__(256) void k_agg4(
    const ushort* __restrict__ hbuf, const int* __restrict__ rowp,
    const int* __restrict__ deg, const int* __restrict__ esrc,
    const float* __restrict__ eaC, const float* __restrict__ a_s,
    const float* __restrict__ a_d, const float* __restrict__ wed,
    const float* __restrict__ bias, const float* __restrict__ bng,
    const float* __restrict__ bnb, const float* __restrict__ bnm,
    const float* __restrict__ bnv, ushort* __restrict__ xout) {
  int tid = threadIdx.x;
  int w = tid >> 6, lane = tid & 63;
  int d = blockIdx.x * 4 + w;
  int start = rowp[d] + d;
  int dg = deg[d];
  int h = lane >> 4;
  float adh = a_d[d * 4 + h];
  float wdh = wed[h];

  int c0 = lane * 4;
  float a0 = 0.f, a1 = 0.f, a2 = 0.f, a3 = 0.f, sz = 0.f, sea = 0.f;
  int k = 0;
  for (; k + 4 <= dg; k += 4) {
    int s0 = esrc[start + k], s1 = esrc[start + k + 1];
    int s2 = esrc[start + k + 2], s3 = esrc[start + k + 3];
    float e0 = eaC[start + k], e1 = eaC[start + k + 1];
    float e2 = eaC[start + k + 2], e3 = eaC[start + k + 3];
    ushort4 v0 = *(const ushort4*)&hbuf[(size_t)s0 * 256 + c0];
    ushort4 v1 = *(const ushort4*)&hbuf[(size_t)s1 * 256 + c0];
    ushort4 v2 = *(const ushort4*)&hbuf[(size_t)s2 * 256 + c0];
    ushort4 v3 = *(const ushort4*)&hbuf[(size_t)s3 * 256 + c0];
    float w0 = __expf(lrelu(a_s[s0 * 4 + h] + adh + e0 * wdh));
    float w1 = __expf(lrelu(a_s[s1 * 4 + h] + adh + e1 * wdh));
    float w2 = __expf(lrelu(a_s[s2 * 4 + h] + adh + e2 * wdh));
    float w3 = __expf(lrelu(a_s[s3 * 4 + h] + adh + e3 * wdh));
    sea += (e0 + e1) + (e2 + e3);
    sz += (w0 + w1) + (w2 + w3);
    a0 += w0 * bu(v0.x) + w1 * bu(v1.x) + w2 * bu(v2.x) + w3 * bu(v3.x);
    a1 += w0 * bu(v0.y) + w1 * bu(v1.y) + w2 * bu(v2.y) + w3 * bu(v3.y);
    a2 += w0 * bu(v0.z) + w1 * bu(v1.z) + w2 * bu(v2.z) + w3 * bu(v3.z);
    a3 += w0 * bu(v0.w) + w1 * bu(v1.w) + w2 * bu(v2.w) + w3 * bu(v3.w);
  }
  for (; k < dg; k++) {
    int s0 = esrc[start + k];
    float e0 = eaC[start + k];
    ushort4 v0 = *(const ushort4*)&hbuf[(size_t)s0 * 256 + c0];
    float w0 = __expf(lrelu(a_s[s0 * 4 + h] + adh + e0 * wdh));
    sea += e0;
    sz += w0;
    a0 += w0 * bu(v0.x); a1 += w0 * bu(v0.y);
    a2 += w0 * bu(v0.z); a3 += w0 * bu(v0.w);
  }
  // self-loop: lea = mean incoming ea, src = d
  {
    float lea = sea / fmaxf((float)dg, 1.f);
    ushort4 v0 = *(const ushort4*)&hbuf[(size_t)d * 256 + c0];
    float w0 = __expf(lrelu(a_s[d * 4 + h] + adh + lea * wdh));
    sz += w0;
    a0 += w0 * bu(v0.x); a1 += w0 * bu(v0.y);
    a2 += w0 * bu(v0.z); a3 += w0 * bu(v0.w);
  }
  float winv = 1.f / (sz + 1e-16f);

  float4 bi = *(const float4*)&bias[c0];
  a0 = a0 * winv + bi.x; a1 = a1 * winv + bi.y;
  a2 = a2 * winv + bi.z; a3 = a3 * winv + bi.w;
  float4 g4 = *(const float4*)&bng[c0], b4 = *(const float4*)&bnb[c0];
  float4 m4 = *(const float4*)&bnm[c0], v4 = *(const float4*)&bnv[c0];
  a0 = fmaxf((a0 - m4.x) * rsqrtf(v4.x + BN_EPS_) * g4.x + b4.x, 0.f);
  a1 = fmaxf((a1 - m4.y) * rsqrtf(v4.y + BN_EPS_) * g4.y + b4.y, 0.f);
  a2 = fmaxf((a2 - m4.z) * rsqrtf(v4.z + BN_EPS_) * g4.z + b4.z, 0.f);
  a3 = fmaxf((a3 - m4.w) * rsqrtf(v4.w + BN_EPS_) * g4.w + b4.w, 0.f);
  ushort4 o = make_ushort4(f2u(a0), f2u(a1), f2u(a2), f2u(a3));
  *(ushort4*)&xout[(size_t)d * 256 + c0] = o;
}

// ---------------- final agg (H=1, 64 ch), inline self-loop ------------------
__global__ __launch_bounds__(256) void k_agg1(
    const ushort* __restrict__ hbuf, const int* __restrict__ rowp,
    const int* __restrict__ deg, const int* __restrict__ esrc,
    const float* __restrict__ eaC, const float* __restrict__ a_s,
    const float* __restrict__ a_d, const float* __restrict__ wed,
    const float* __restrict__ bias, float* __restrict__ xout) {
  int tid = threadIdx.x;
  int w = tid >> 6, lane = tid & 63;
  int d = blockIdx.x * 4 + w;
  int start = rowp[d] + d;
  int dg = deg[d];
  float adh = a_d[d];
  float wdh = wed[0];

  float acc = 0.f, sz = 0.f, sea = 0.f;
  int k = 0;
  for (; k + 4 <= dg; k += 4) {
    int s0 = esrc[start + k], s1 = esrc[start + k + 1];
    int s2 = esrc[start + k + 2], s3 = esrc[start + k + 3];
    float e0 = eaC[start + k], e1 = eaC[start + k + 1];
    float e2 = eaC[start + k + 2], e3 = eaC[start + k + 3];
    float v0 = bu(hbuf[(size_t)s0 * 64 + lane]);
    float v1 = bu(hbuf[(size_t)s1 * 64 + lane]);
    float v2 = bu(hbuf[(size_t)s2 * 64 + lane]);
    float v3 = bu(hbuf[(size_t)s3 * 64 + lane]);
    float w0 = __expf(lrelu(a_s[s0] + adh + e0 * wdh));
    float w1 = __expf(lrelu(a_s[s1] + adh + e1 * wdh));
    float w2 = __expf(lrelu(a_s[s2] + adh + e2 * wdh));
    float w3 = __expf(lrelu(a_s[s3] + adh + e3 * wdh));
    sea += (e0 + e1) + (e2 + e3);
    sz += (w0 + w1) + (w2 + w3);
    acc += w0 * v0 + w1 * v1 + w2 * v2 + w3 * v3;
  }
  for (; k < dg; k++) {
    int s0 = esrc[start + k];
    float e0 = eaC[start + k];
    float w0 = __expf(lrelu(a_s[s0] + adh + e0 * wdh));
    sea += e0;
    sz += w0;
    acc += w0 * bu(hbuf[(size_t)s0 * 64 + lane]);
  }
  {
    float lea = sea / fmaxf((float)dg, 1.f);
    float w0 = __expf(lrelu(a_s[d] + adh + lea * wdh));
    sz += w0;
    acc += w0 * bu(hbuf[(size_t)d * 64 + lane]);
  }
  acc = acc / (sz + 1e-16f) + bias[lane];
  xout[(size_t)d * 64 + lane] = acc;
}

// ---------------- fused mean-pool + MLP head ----------------
__global__ void k_poolhead(const float* __restrict__ xin,
                           const float* __restrict__ cw1, const float* __restrict__ cb1,
                           const float* __restrict__ cw2, const float* __restrict__ cb2,
                           float* __restrict__ out) {
  __shared__ float part[4][64];
  __shared__ float gb[64], hb[64];
  int g = blockIdx.x, tid = threadIdx.x;
  int c = tid & 63, w = tid >> 6;
  float acc = 0.f;
  size_t base = (size_t)g * kNPG * 64;
  for (int n = w; n < kNPG; n += 4) acc += xin[base + (size_t)n * 64 + c];
  part[w][c] = acc;
  __syncthreads();
  if (tid < 64) {
    float s = (part[0][c] + part[1][c]) + (part[2][c] + part[3][c]);
    gb[c] = s * (1.f / kNPG);
  }
  __syncthreads();
  if (tid < 64) {
    float s = cb1[c];
#pragma unroll 8
    for (int i = 0; i < 64; i++) s += gb[i] * cw1[i * 64 + c];
    s = 0.5f * s * (1.f + erff(s * 0.70710678118654752f));  // exact GELU
    hb[c] = s;
  }
  __syncthreads();
  if (tid < 2) {
    float o = cb2[tid];
    for (int i = 0; i < 64; i++) o += hb[i] * cw2[i * 2 + tid];
    out[g * 2 + tid] = o;
  }
}

// ---------------- launch ----------------

extern "C" void kernel_launch(void* const* d_in, const int* in_sizes, int n_in,
                              void* d_out, int out_size, void* d_ws, size_t ws_size,
                              hipStream_t stream) {
  (void)in_sizes; (void)n_in; (void)out_size; (void)ws_size;
  const float* x  = (const float*)d_in[0];
  const int* ei   = (const int*)d_in[1];
  const float* ea = (const float*)d_in[2];
  const float *W[3], *as_[3], *ad_[3], *We[3], *ae[3], *bi[3];
  for (int l = 0; l < 3; l++) {
    W[l]   = (const float*)d_in[4 + l * 6 + 0];
    as_[l] = (const float*)d_in[4 + l * 6 + 1];
    ad_[l] = (const float*)d_in[4 + l * 6 + 2];
    We[l]  = (const float*)d_in[4 + l * 6 + 3];
    ae[l]  = (const float*)d_in[4 + l * 6 + 4];
    bi[l]  = (const float*)d_in[4 + l * 6 + 5];
  }
  const float* bng = (const float*)d_in[22];
  const float* bnb = (const float*)d_in[23];
  const float* bnm = (const float*)d_in[24];
  const float* bnv = (const float*)d_in[25];
  const float* cw1 = (const float*)d_in[26];
  const float* cb1 = (const float*)d_in[27];
  const float* cw2 = (const float*)d_in[28];
  const float* cb2 = (const float*)d_in[29];

  char* p = (char*)d_ws;
  auto alloc = [&](size_t bytes) -> void* {
    void* r = (void*)p;
    p += (bytes + 255) & ~(size_t)255;
    return r;
  };
  ushort* x2b   = (ushort*)alloc((size_t)kN * kIN2 * 2);
  ushort* hbufb = (ushort*)alloc((size_t)kN * 256 * 2);
  ushort* xbA   = (ushort*)alloc((size_t)kN * 256 * 2);
  ushort* xbB   = (ushort*)alloc((size_t)kN * 256 * 2);
  float*  fbuf  = (float*)alloc((size_t)kN * 64 * 4);
  ushort* Wt0   = (ushort*)alloc((size_t)kIN2 * 256 * 2);
  ushort* Wt1   = (ushort*)alloc((size_t)256 * 256 * 2);
  ushort* Wt2   = (ushort*)alloc((size_t)256 * 64 * 2);
  float* a_s    = (float*)alloc((size_t)kN * 4 * 4);
  float* a_d    = (float*)alloc((size_t)kN * 4 * 4);
  int* rowp     = (int*)alloc((size_t)kN * 4);
  int* esrc     = (int*)alloc((size_t)(kE + kN) * 4);
  float* eaC    = (float*)alloc((size_t)(kE + kN) * 4);
  int* epos     = (int*)alloc((size_t)kE * 4);
  int* blockcnt = (int*)alloc((size_t)kHB * kN * 4);   // 6.55 MB
  float* wed    = (float*)alloc(256);
  int* deg      = (int*)alloc((size_t)kN * 4);

  // 1: fused prep (prep_x x4 | Wt + wedot)
  k_pre<<<5000 + 720 + 3, 256, 0, stream>>>(x, x2b, W[0], Wt0, W[1], Wt1,
                                            W[2], Wt2, We[0], ae[0], We[1], ae[1],
                                            We[2], ae[2], wed);
  // 2-5: atomic-free CSR build
  k_hist<<<kHB, 1024, 0, stream>>>(ei, epos, blockcnt);
  k_colscan<<<kN / 256, 256, 0, stream>>>(blockcnt, deg);
  k_scan_all<<<1, 1024, 0, stream>>>(deg, rowp);
  k_scatter_n<<<(kE + 255) / 256, 256, 0, stream>>>(ei, ea, rowp, epos, blockcnt,
                                                    esrc, eaC);
  // 6: layer-0 GEMM (K=400)
  dim3 gg32(1, kN / 32);
  k_gemm_f<256, 32><<<gg32, 256, 0, stream>>>(x2b, Wt0, hbufb, as_[0], ad_[0],
                                              a_s, a_d, kIN2);
  // 7: agg layer0
  k_agg4<<<kN / 4, 256, 0, stream>>>(hbufb, rowp, deg, esrc, eaC, a_s, a_d,
                                     &wed[0], bi[0], bng, bnb, bnm, bnv, xbA);
  // 8: gemm layer1
  k_gemm_f<256, 32><<<gg32, 256, 0, stream>>>(xbA, Wt1, hbufb, as_[1], ad_[1],
                                              a_s, a_d, 256);
  // 9: agg layer1
  k_agg4<<<kN / 4, 256, 0, stream>>>(hbufb, rowp, deg, esrc, eaC, a_s, a_d,
                                     &wed[4], bi[1], bng, bnb, bnm, bnv, xbB);
  // 10: gemm layer2
  dim3 gg64(1, kN / 64);
  k_gemm_f<64, 64><<<gg64, 256, 0, stream>>>(xbB, Wt2, hbufb, as_[2], ad_[2],
                                             a_s, a_d, 256);
  // 11: agg layer2 (H=1)
  k_agg1<<<kN / 4, 256, 0, stream>>>(hbufb, rowp, deg, esrc, eaC, a_s, a_d,
                                     &wed[8], bi[2], fbuf);
  // 12: pool + MLP head
  k_poolhead<<<kG, 256, 0, stream>>>(fbuf, cw1, cb1, cw2, cb2, (float*)d_out);
}